// Round 1
// baseline (619.761 us; speedup 1.0000x reference)
//
#include <hip/hip_runtime.h>
#include <hip/hip_bf16.h>

typedef unsigned short u16;
typedef __attribute__((ext_vector_type(8))) short bf16x8;
typedef __attribute__((ext_vector_type(4))) float f32x4;

#define N_TOK 4096
#define DMODEL 3072
#define NH 16
#define DHEAD 64
#define INNER 1024
#define SCALE_LOG2E 0.18033688011112042f  /* (1/8) * log2(e) */

__device__ __forceinline__ u16 f2bf(float f) {
    union { float f; unsigned u; } un; un.f = f;
    unsigned r = un.u + 0x7fffu + ((un.u >> 16) & 1u);
    return (u16)(r >> 16);
}
__device__ __forceinline__ float bf2f(u16 u) {
    union { unsigned u; float f; } x; x.u = ((unsigned)u) << 16; return x.f;
}
__device__ __forceinline__ void load_lds16(const u16* g, u16* l) {
    __builtin_amdgcn_global_load_lds(
        (const __attribute__((address_space(1))) unsigned int*)g,
        (__attribute__((address_space(3))) unsigned int*)l, 16, 0, 0);
}

// ---------------- LayerNorm: x f32 [4096,3072] -> xn bf16 ----------------
__global__ __launch_bounds__(256) void ln_kernel(const float* __restrict__ x,
                                                 const float* __restrict__ g,
                                                 const float* __restrict__ b,
                                                 u16* __restrict__ xn) {
    int row = blockIdx.x;
    int tid = threadIdx.x;
    const float4* xr = (const float4*)(x + (size_t)row * DMODEL);
    float4 v[3];
    float s = 0.f, ss = 0.f;
#pragma unroll
    for (int i = 0; i < 3; ++i) {
        v[i] = xr[i * 256 + tid];
        s  += v[i].x + v[i].y + v[i].z + v[i].w;
        ss += v[i].x * v[i].x + v[i].y * v[i].y + v[i].z * v[i].z + v[i].w * v[i].w;
    }
#pragma unroll
    for (int off = 32; off; off >>= 1) {
        s  += __shfl_xor(s, off);
        ss += __shfl_xor(ss, off);
    }
    __shared__ float red[8];
    int wid = tid >> 6, lane = tid & 63;
    if (lane == 0) { red[wid] = s; red[wid + 4] = ss; }
    __syncthreads();
    s  = red[0] + red[1] + red[2] + red[3];
    ss = red[4] + red[5] + red[6] + red[7];
    float mean = s * (1.f / DMODEL);
    float var  = ss * (1.f / DMODEL) - mean * mean;
    float rstd = rsqrtf(var + 1e-5f);
    ushort4* orow = (ushort4*)(xn + (size_t)row * DMODEL);
#pragma unroll
    for (int i = 0; i < 3; ++i) {
        float4 gg = ((const float4*)g)[i * 256 + tid];
        float4 bb = ((const float4*)b)[i * 256 + tid];
        ushort4 o;
        o.x = f2bf((v[i].x - mean) * rstd * gg.x + bb.x);
        o.y = f2bf((v[i].y - mean) * rstd * gg.y + bb.y);
        o.z = f2bf((v[i].z - mean) * rstd * gg.z + bb.z);
        o.w = f2bf((v[i].w - mean) * rstd * gg.w + bb.w);
        orow[i * 256 + tid] = o;
    }
}

// ---------------- f32 -> bf16 convert ----------------
__global__ __launch_bounds__(256) void cvt_bf16(const float* __restrict__ in,
                                                u16* __restrict__ out, int n4) {
    int i = blockIdx.x * 256 + threadIdx.x;
    if (i < n4) {
        float4 v = ((const float4*)in)[i];
        ushort4 o;
        o.x = f2bf(v.x); o.y = f2bf(v.y); o.z = f2bf(v.z); o.w = f2bf(v.w);
        ((ushort4*)out)[i] = o;
    }
}

// ---------------- GEMM C = A * B^T ; A[M,K], B[N,K] bf16, C f32 or bf16 ---
// 128x128 tile, BK=32, 256 thr (4 waves, 2x2), 16x16x32 bf16 MFMA
template <int CBF16>
__global__ __launch_bounds__(256) void gemm_bt(const u16* __restrict__ A,
                                               const u16* __restrict__ B,
                                               void* __restrict__ C,
                                               int M, int Nn, int K) {
    __shared__ u16 As[128 * 32];
    __shared__ u16 Bs[128 * 32];
    int tid = threadIdx.x;
    int lane = tid & 63, wid = tid >> 6;
    int wm = wid >> 1, wn = wid & 1;
    int l15 = lane & 15, quad = lane >> 4;
    int m0 = blockIdx.y * 128, n0 = blockIdx.x * 128;

    f32x4 zero4 = {0.f, 0.f, 0.f, 0.f};
    f32x4 acc[4][4];
#pragma unroll
    for (int i = 0; i < 4; ++i)
#pragma unroll
        for (int j = 0; j < 4; ++j) acc[i][j] = zero4;

    const u16* Ab = A + (size_t)m0 * K;
    const u16* Bb = B + (size_t)n0 * K;
    int row0 = tid >> 2, c0 = (tid & 3) * 8;
    int row1 = row0 + 64, c1 = c0;

    for (int k0 = 0; k0 < K; k0 += 32) {
        load_lds16(Ab + (size_t)row0 * K + k0 + c0, &As[wid * 512]);
        load_lds16(Ab + (size_t)row1 * K + k0 + c1, &As[2048 + wid * 512]);
        load_lds16(Bb + (size_t)row0 * K + k0 + c0, &Bs[wid * 512]);
        load_lds16(Bb + (size_t)row1 * K + k0 + c1, &Bs[2048 + wid * 512]);
        __syncthreads();
        bf16x8 a[4], b[4];
#pragma unroll
        for (int t = 0; t < 4; ++t) {
            a[t] = *(const bf16x8*)&As[(wm * 64 + t * 16 + l15) * 32 + quad * 8];
            b[t] = *(const bf16x8*)&Bs[(wn * 64 + t * 16 + l15) * 32 + quad * 8];
        }
#pragma unroll
        for (int mt = 0; mt < 4; ++mt)
#pragma unroll
            for (int nt = 0; nt < 4; ++nt)
                acc[mt][nt] = __builtin_amdgcn_mfma_f32_16x16x32_bf16(a[mt], b[nt], acc[mt][nt], 0, 0, 0);
        __syncthreads();
    }
#pragma unroll
    for (int mt = 0; mt < 4; ++mt)
#pragma unroll
        for (int nt = 0; nt < 4; ++nt)
#pragma unroll
            for (int r = 0; r < 4; ++r) {
                int rr = m0 + wm * 64 + mt * 16 + quad * 4 + r;
                int cc = n0 + wn * 64 + nt * 16 + l15;
                if (CBF16)
                    ((u16*)C)[(size_t)rr * Nn + cc] = f2bf(acc[mt][nt][r]);
                else
                    ((float*)C)[(size_t)rr * Nn + cc] = acc[mt][nt][r];
            }
}

// ---------------- RoPE on q,k + reshape to [H,N,DH] ----------------
__global__ __launch_bounds__(256) void rope_qk(const u16* __restrict__ qkv,
                                               const float* __restrict__ pe,
                                               u16* __restrict__ Qr,
                                               u16* __restrict__ Kr) {
    int n = blockIdx.x;
    int tid = threadIdx.x;
    const u16* qrow = qkv + (size_t)n * DMODEL;
    const float4* pen = (const float4*)(pe + (size_t)n * 128);
#pragma unroll
    for (int it = 0; it < 2; ++it) {
        int p = it * 256 + tid;      // pair index 0..511
        int h = p >> 5, i = p & 31;
        float4 w = pen[i];
        size_t obase = ((size_t)h * N_TOK + n) * DHEAD + 2 * i;
        // q
        unsigned qq = *(const unsigned*)&qrow[h * 64 + 2 * i];
        float q0 = bf2f((u16)qq), q1 = bf2f((u16)(qq >> 16));
        unsigned o0 = f2bf(w.x * q0 + w.y * q1);
        unsigned o1 = f2bf(w.z * q0 + w.w * q1);
        *(unsigned*)&Qr[obase] = o0 | (o1 << 16);
        // k
        unsigned kk = *(const unsigned*)&qrow[INNER + h * 64 + 2 * i];
        float k0 = bf2f((u16)kk), k1 = bf2f((u16)(kk >> 16));
        unsigned p0 = f2bf(w.x * k0 + w.y * k1);
        unsigned p1 = f2bf(w.z * k0 + w.w * k1);
        *(unsigned*)&Kr[obase] = p0 | (p1 << 16);
    }
}

// ---------------- V transpose: Vt[h][d][n] = qkv[n][2048 + h*64 + d] ------
__global__ __launch_bounds__(256) void v_transpose(const u16* __restrict__ qkv,
                                                   u16* __restrict__ Vt) {
    __shared__ u16 t[64][65];
    int n0 = blockIdx.x * 64;
    int h = blockIdx.y;
    int tid = threadIdx.x;
#pragma unroll
    for (int it = 0; it < 4; ++it) {
        int nr = it * 16 + (tid >> 4);
        int dc = (tid & 15) * 4;
        ushort4 v = *(const ushort4*)&qkv[(size_t)(n0 + nr) * DMODEL + 2 * INNER + h * 64 + dc];
        t[dc + 0][nr] = v.x; t[dc + 1][nr] = v.y; t[dc + 2][nr] = v.z; t[dc + 3][nr] = v.w;
    }
    __syncthreads();
#pragma unroll
    for (int it = 0; it < 4; ++it) {
        int dr = it * 16 + (tid >> 4);
        int nc = (tid & 15) * 4;
        ushort4 v;
        v.x = t[dr][nc]; v.y = t[dr][nc + 1]; v.z = t[dr][nc + 2]; v.w = t[dr][nc + 3];
        *(ushort4*)&Vt[((size_t)h * 64 + dr) * N_TOK + n0 + nc] = v;
    }
}

// ---------------- Flash attention ----------------
// grid (32 qtiles, 16 heads); 256 thr = 4 waves; wave owns 32 q-rows.
// Q,K: [H][N][64] bf16; Vt: [H][64][N] bf16; O: [N][INNER] bf16
__global__ __launch_bounds__(256) void flash_attn(const u16* __restrict__ Q,
                                                  const u16* __restrict__ K,
                                                  const u16* __restrict__ Vt,
                                                  u16* __restrict__ O) {
    __shared__ u16 Ks[64 * 64];
    __shared__ u16 Vs[64 * 64];
    __shared__ u16 Ps[4][32 * 64];
    int tid = threadIdx.x, lane = tid & 63, wid = tid >> 6;
    int l15 = lane & 15, quad = lane >> 4;
    int h = blockIdx.y;
    int q0 = blockIdx.x * 128 + wid * 32;
    const u16* Qh = Q + (size_t)h * N_TOK * DHEAD;
    const u16* Kh = K + (size_t)h * N_TOK * DHEAD;
    const u16* Vh = Vt + (size_t)h * DHEAD * N_TOK;

    f32x4 zero4 = {0.f, 0.f, 0.f, 0.f};
    bf16x8 aq[2][2];
#pragma unroll
    for (int mt = 0; mt < 2; ++mt)
#pragma unroll
        for (int kc = 0; kc < 2; ++kc)
            aq[mt][kc] = *(const bf16x8*)&Qh[(size_t)(q0 + mt * 16 + l15) * DHEAD + kc * 32 + quad * 8];

    f32x4 o[2][4];
    float mrow[2][4], lrow[2][4];
#pragma unroll
    for (int mt = 0; mt < 2; ++mt) {
#pragma unroll
        for (int dt = 0; dt < 4; ++dt) o[mt][dt] = zero4;
#pragma unroll
        for (int r = 0; r < 4; ++r) { mrow[mt][r] = -1e30f; lrow[mt][r] = 0.f; }
    }

    int r0 = tid >> 3, c0 = (tid & 7) * 8;

    for (int kt = 0; kt < N_TOK; kt += 64) {
        load_lds16(&Kh[(size_t)(kt + r0) * DHEAD + c0], &Ks[wid * 512]);
        load_lds16(&Kh[(size_t)(kt + r0 + 32) * DHEAD + c0], &Ks[2048 + wid * 512]);
        load_lds16(&Vh[(size_t)r0 * N_TOK + kt + c0], &Vs[wid * 512]);
        load_lds16(&Vh[(size_t)(r0 + 32) * N_TOK + kt + c0], &Vs[2048 + wid * 512]);
        __syncthreads();

        // S = Q K^T  (per wave: 32 q rows x 64 keys)
        bf16x8 bk[4][2];
#pragma unroll
        for (int nt = 0; nt < 4; ++nt)
#pragma unroll
            for (int kc = 0; kc < 2; ++kc)
                bk[nt][kc] = *(const bf16x8*)&Ks[(nt * 16 + l15) * 64 + kc * 32 + quad * 8];
        f32x4 s[2][4];
#pragma unroll
        for (int mt = 0; mt < 2; ++mt)
#pragma unroll
            for (int nt = 0; nt < 4; ++nt) {
                f32x4 t0 = __builtin_amdgcn_mfma_f32_16x16x32_bf16(aq[mt][0], bk[nt][0], zero4, 0, 0, 0);
                s[mt][nt] = __builtin_amdgcn_mfma_f32_16x16x32_bf16(aq[mt][1], bk[nt][1], t0, 0, 0, 0);
            }

        // online softmax (rows live in lanes sharing quad; cols across l15 & nt)
#pragma unroll
        for (int mt = 0; mt < 2; ++mt)
#pragma unroll
            for (int r = 0; r < 4; ++r) {
                float mx = fmaxf(fmaxf(s[mt][0][r], s[mt][1][r]), fmaxf(s[mt][2][r], s[mt][3][r]));
                mx = fmaxf(mx, __shfl_xor(mx, 1));
                mx = fmaxf(mx, __shfl_xor(mx, 2));
                mx = fmaxf(mx, __shfl_xor(mx, 4));
                mx = fmaxf(mx, __shfl_xor(mx, 8));
                float mold = mrow[mt][r];
                float mnew = fmaxf(mold, mx);
                mrow[mt][r] = mnew;
                float alpha = exp2f((mold - mnew) * SCALE_LOG2E);
                float rsum = 0.f;
#pragma unroll
                for (int nt = 0; nt < 4; ++nt) {
                    float p = exp2f((s[mt][nt][r] - mnew) * SCALE_LOG2E);
                    s[mt][nt][r] = p;
                    rsum += p;
                }
                rsum += __shfl_xor(rsum, 1);
                rsum += __shfl_xor(rsum, 2);
                rsum += __shfl_xor(rsum, 4);
                rsum += __shfl_xor(rsum, 8);
                lrow[mt][r] = lrow[mt][r] * alpha + rsum;
#pragma unroll
                for (int dt = 0; dt < 4; ++dt) o[mt][dt][r] *= alpha;
            }

        // P: C-layout -> LDS -> A-operand layout
#pragma unroll
        for (int mt = 0; mt < 2; ++mt)
#pragma unroll
            for (int nt = 0; nt < 4; ++nt)
#pragma unroll
                for (int r = 0; r < 4; ++r)
                    Ps[wid][(mt * 16 + quad * 4 + r) * 64 + nt * 16 + l15] = f2bf(s[mt][nt][r]);

        bf16x8 bv[4][2];
#pragma unroll
        for (int dt = 0; dt < 4; ++dt)
#pragma unroll
            for (int kc = 0; kc < 2; ++kc)
                bv[dt][kc] = *(const bf16x8*)&Vs[(dt * 16 + l15) * 64 + kc * 32 + quad * 8];
#pragma unroll
        for (int mt = 0; mt < 2; ++mt) {
            bf16x8 ap0 = *(const bf16x8*)&Ps[wid][(mt * 16 + l15) * 64 + quad * 8];
            bf16x8 ap1 = *(const bf16x8*)&Ps[wid][(mt * 16 + l15) * 64 + 32 + quad * 8];
#pragma unroll
            for (int dt = 0; dt < 4; ++dt) {
                o[mt][dt] = __builtin_amdgcn_mfma_f32_16x16x32_bf16(ap0, bv[dt][0], o[mt][dt], 0, 0, 0);
                o[mt][dt] = __builtin_amdgcn_mfma_f32_16x16x32_bf16(ap1, bv[dt][1], o[mt][dt], 0, 0, 0);
            }
        }
        __syncthreads();
    }

    // epilogue: O[n][h*64+d] = o / l
#pragma unroll
    for (int mt = 0; mt < 2; ++mt)
#pragma unroll
        for (int dt = 0; dt < 4; ++dt)
#pragma unroll
            for (int r = 0; r < 4; ++r) {
                int n = q0 + mt * 16 + quad * 4 + r;
                int d = dt * 16 + l15;
                O[(size_t)n * INNER + h * 64 + d] = f2bf(o[mt][dt][r] / lrow[mt][r]);
            }
}

extern "C" void kernel_launch(void* const* d_in, const int* in_sizes, int n_in,
                              void* d_out, int out_size, void* d_ws, size_t ws_size,
                              hipStream_t stream) {
    const float* x     = (const float*)d_in[0];
    const float* pe    = (const float*)d_in[1];
    const float* w_qkv = (const float*)d_in[2];
    const float* w_out = (const float*)d_in[3];
    const float* ln_g  = (const float*)d_in[4];
    const float* ln_b  = (const float*)d_in[5];
    float* out = (float*)d_out;

    char* ws = (char*)d_ws;
    u16* xn  = (u16*)ws;  ws += (size_t)N_TOK * DMODEL * 2;       // 25 MB
    u16* wq  = (u16*)ws;  ws += (size_t)3 * INNER * DMODEL * 2;   // 18.9 MB
    u16* wo  = (u16*)ws;  ws += (size_t)DMODEL * INNER * 2;       // 6.3 MB
    u16* qkv = (u16*)ws;  ws += (size_t)N_TOK * DMODEL * 2;       // 25 MB
    u16* Qr  = (u16*)ws;  ws += (size_t)NH * N_TOK * DHEAD * 2;   // 8.4 MB
    u16* Kr  = (u16*)ws;  ws += (size_t)NH * N_TOK * DHEAD * 2;   // 8.4 MB
    u16* Vt  = (u16*)ws;  ws += (size_t)NH * DHEAD * N_TOK * 2;   // 8.4 MB
    u16* Ob  = (u16*)ws;  ws += (size_t)N_TOK * INNER * 2;        // 8.4 MB

    ln_kernel<<<N_TOK, 256, 0, stream>>>(x, ln_g, ln_b, xn);
    {
        int n4 = 3 * INNER * DMODEL / 4;
        cvt_bf16<<<(n4 + 255) / 256, 256, 0, stream>>>(w_qkv, wq, n4);
    }
    {
        int n4 = DMODEL * INNER / 4;
        cvt_bf16<<<(n4 + 255) / 256, 256, 0, stream>>>(w_out, wo, n4);
    }
    gemm_bt<1><<<dim3(DMODEL / 128, N_TOK / 128), 256, 0, stream>>>(xn, wq, qkv, N_TOK, DMODEL, DMODEL);
    rope_qk<<<N_TOK, 256, 0, stream>>>(qkv, pe, Qr, Kr);
    v_transpose<<<dim3(N_TOK / 64, NH), 256, 0, stream>>>(qkv, Vt);
    flash_attn<<<dim3(N_TOK / 128, NH), 256, 0, stream>>>(Qr, Kr, Vt, Ob);
    gemm_bt<0><<<dim3(DMODEL / 128, N_TOK / 128), 256, 0, stream>>>(Ob, wo, out, N_TOK, DMODEL, INNER);
}

// Round 2
// 490.122 us; speedup vs baseline: 1.2645x; 1.2645x over previous
//
#include <hip/hip_runtime.h>
#include <hip/hip_bf16.h>

typedef unsigned short u16;
typedef __attribute__((ext_vector_type(8))) short bf16x8;
typedef __attribute__((ext_vector_type(4))) float f32x4;

#define N_TOK 4096
#define DMODEL 3072
#define NH 16
#define DHEAD 64
#define INNER 1024
#define SCALE_LOG2E 0.18033688011112042f  /* (1/8) * log2(e) */

__device__ __forceinline__ u16 f2bf(float f) {
    union { float f; unsigned u; } un; un.f = f;
    unsigned r = un.u + 0x7fffu + ((un.u >> 16) & 1u);
    return (u16)(r >> 16);
}
__device__ __forceinline__ float bf2f(u16 u) {
    union { unsigned u; float f; } x; x.u = ((unsigned)u) << 16; return x.f;
}
__device__ __forceinline__ void load_lds16(const u16* g, u16* l) {
    __builtin_amdgcn_global_load_lds(
        (const __attribute__((address_space(1))) unsigned int*)g,
        (__attribute__((address_space(3))) unsigned int*)l, 16, 0, 0);
}

// ---------------- LayerNorm: x f32 [4096,3072] -> xn bf16 ----------------
__global__ __launch_bounds__(256) void ln_kernel(const float* __restrict__ x,
                                                 const float* __restrict__ g,
                                                 const float* __restrict__ b,
                                                 u16* __restrict__ xn) {
    int row = blockIdx.x;
    int tid = threadIdx.x;
    const float4* xr = (const float4*)(x + (size_t)row * DMODEL);
    float4 v[3];
    float s = 0.f, ss = 0.f;
#pragma unroll
    for (int i = 0; i < 3; ++i) {
        v[i] = xr[i * 256 + tid];
        s  += v[i].x + v[i].y + v[i].z + v[i].w;
        ss += v[i].x * v[i].x + v[i].y * v[i].y + v[i].z * v[i].z + v[i].w * v[i].w;
    }
#pragma unroll
    for (int off = 32; off; off >>= 1) {
        s  += __shfl_xor(s, off);
        ss += __shfl_xor(ss, off);
    }
    __shared__ float red[8];
    int wid = tid >> 6, lane = tid & 63;
    if (lane == 0) { red[wid] = s; red[wid + 4] = ss; }
    __syncthreads();
    s  = red[0] + red[1] + red[2] + red[3];
    ss = red[4] + red[5] + red[6] + red[7];
    float mean = s * (1.f / DMODEL);
    float var  = ss * (1.f / DMODEL) - mean * mean;
    float rstd = rsqrtf(var + 1e-5f);
    ushort4* orow = (ushort4*)(xn + (size_t)row * DMODEL);
#pragma unroll
    for (int i = 0; i < 3; ++i) {
        float4 gg = ((const float4*)g)[i * 256 + tid];
        float4 bb = ((const float4*)b)[i * 256 + tid];
        ushort4 o;
        o.x = f2bf((v[i].x - mean) * rstd * gg.x + bb.x);
        o.y = f2bf((v[i].y - mean) * rstd * gg.y + bb.y);
        o.z = f2bf((v[i].z - mean) * rstd * gg.z + bb.z);
        o.w = f2bf((v[i].w - mean) * rstd * gg.w + bb.w);
        orow[i * 256 + tid] = o;
    }
}

// ---------------- f32 -> bf16 convert ----------------
__global__ __launch_bounds__(256) void cvt_bf16(const float* __restrict__ in,
                                                u16* __restrict__ out, int n4) {
    int i = blockIdx.x * 256 + threadIdx.x;
    if (i < n4) {
        float4 v = ((const float4*)in)[i];
        ushort4 o;
        o.x = f2bf(v.x); o.y = f2bf(v.y); o.z = f2bf(v.z); o.w = f2bf(v.w);
        ((ushort4*)out)[i] = o;
    }
}

// ---------------- GEMM C = A * B^T ; A[M,K], B[N,K] bf16, C f32 or bf16 ---
template <int CBF16>
__global__ __launch_bounds__(256) void gemm_bt(const u16* __restrict__ A,
                                               const u16* __restrict__ B,
                                               void* __restrict__ C,
                                               int M, int Nn, int K) {
    __shared__ u16 As[128 * 32];
    __shared__ u16 Bs[128 * 32];
    int tid = threadIdx.x;
    int lane = tid & 63, wid = tid >> 6;
    int wm = wid >> 1, wn = wid & 1;
    int l15 = lane & 15, quad = lane >> 4;
    int m0 = blockIdx.y * 128, n0 = blockIdx.x * 128;

    f32x4 zero4 = {0.f, 0.f, 0.f, 0.f};
    f32x4 acc[4][4];
#pragma unroll
    for (int i = 0; i < 4; ++i)
#pragma unroll
        for (int j = 0; j < 4; ++j) acc[i][j] = zero4;

    const u16* Ab = A + (size_t)m0 * K;
    const u16* Bb = B + (size_t)n0 * K;
    int row0 = tid >> 2, c0 = (tid & 3) * 8;
    int row1 = row0 + 64, c1 = c0;

    for (int k0 = 0; k0 < K; k0 += 32) {
        load_lds16(Ab + (size_t)row0 * K + k0 + c0, &As[wid * 512]);
        load_lds16(Ab + (size_t)row1 * K + k0 + c1, &As[2048 + wid * 512]);
        load_lds16(Bb + (size_t)row0 * K + k0 + c0, &Bs[wid * 512]);
        load_lds16(Bb + (size_t)row1 * K + k0 + c1, &Bs[2048 + wid * 512]);
        __syncthreads();
        bf16x8 a[4], b[4];
#pragma unroll
        for (int t = 0; t < 4; ++t) {
            a[t] = *(const bf16x8*)&As[(wm * 64 + t * 16 + l15) * 32 + quad * 8];
            b[t] = *(const bf16x8*)&Bs[(wn * 64 + t * 16 + l15) * 32 + quad * 8];
        }
#pragma unroll
        for (int mt = 0; mt < 4; ++mt)
#pragma unroll
            for (int nt = 0; nt < 4; ++nt)
                acc[mt][nt] = __builtin_amdgcn_mfma_f32_16x16x32_bf16(a[mt], b[nt], acc[mt][nt], 0, 0, 0);
        __syncthreads();
    }
#pragma unroll
    for (int mt = 0; mt < 4; ++mt)
#pragma unroll
        for (int nt = 0; nt < 4; ++nt)
#pragma unroll
            for (int r = 0; r < 4; ++r) {
                int rr = m0 + wm * 64 + mt * 16 + quad * 4 + r;
                int cc = n0 + wn * 64 + nt * 16 + l15;
                if (CBF16)
                    ((u16*)C)[(size_t)rr * Nn + cc] = f2bf(acc[mt][nt][r]);
                else
                    ((float*)C)[(size_t)rr * Nn + cc] = acc[mt][nt][r];
            }
}

// ---------------- RoPE on q,k + reshape to [H,N,DH] ----------------
__global__ __launch_bounds__(256) void rope_qk(const u16* __restrict__ qkv,
                                               const float* __restrict__ pe,
                                               u16* __restrict__ Qr,
                                               u16* __restrict__ Kr) {
    int n = blockIdx.x;
    int tid = threadIdx.x;
    const u16* qrow = qkv + (size_t)n * DMODEL;
    const float4* pen = (const float4*)(pe + (size_t)n * 128);
#pragma unroll
    for (int it = 0; it < 2; ++it) {
        int p = it * 256 + tid;      // pair index 0..511
        int h = p >> 5, i = p & 31;
        float4 w = pen[i];
        size_t obase = ((size_t)h * N_TOK + n) * DHEAD + 2 * i;
        unsigned qq = *(const unsigned*)&qrow[h * 64 + 2 * i];
        float q0 = bf2f((u16)qq), q1 = bf2f((u16)(qq >> 16));
        unsigned o0 = f2bf(w.x * q0 + w.y * q1);
        unsigned o1 = f2bf(w.z * q0 + w.w * q1);
        *(unsigned*)&Qr[obase] = o0 | (o1 << 16);
        unsigned kk = *(const unsigned*)&qrow[INNER + h * 64 + 2 * i];
        float k0 = bf2f((u16)kk), k1 = bf2f((u16)(kk >> 16));
        unsigned p0 = f2bf(w.x * k0 + w.y * k1);
        unsigned p1 = f2bf(w.z * k0 + w.w * k1);
        *(unsigned*)&Kr[obase] = p0 | (p1 << 16);
    }
}

// ---------------- V transpose: Vt[h][d][n] = qkv[n][2048 + h*64 + d] ------
__global__ __launch_bounds__(256) void v_transpose(const u16* __restrict__ qkv,
                                                   u16* __restrict__ Vt) {
    __shared__ u16 t[64][65];
    int n0 = blockIdx.x * 64;
    int h = blockIdx.y;
    int tid = threadIdx.x;
#pragma unroll
    for (int it = 0; it < 4; ++it) {
        int nr = it * 16 + (tid >> 4);
        int dc = (tid & 15) * 4;
        ushort4 v = *(const ushort4*)&qkv[(size_t)(n0 + nr) * DMODEL + 2 * INNER + h * 64 + dc];
        t[dc + 0][nr] = v.x; t[dc + 1][nr] = v.y; t[dc + 2][nr] = v.z; t[dc + 3][nr] = v.w;
    }
    __syncthreads();
#pragma unroll
    for (int it = 0; it < 4; ++it) {
        int dr = it * 16 + (tid >> 4);
        int nc = (tid & 15) * 4;
        ushort4 v;
        v.x = t[dr][nc]; v.y = t[dr][nc + 1]; v.z = t[dr][nc + 2]; v.w = t[dr][nc + 3];
        *(ushort4*)&Vt[((size_t)h * 64 + dr) * N_TOK + n0 + nc] = v;
    }
}

// ---------------- Flash attention (transposed-S scheme) ----------------
// grid (32 qtiles, 16 heads); 256 thr = 4 waves; wave owns 32 q-rows.
// S^T = mfma(A=K, B=Q): lane holds key=ntK*16+quad*4+r, q=mtQ*16+l15.
// O^T = mfma(A=V^T, B=P^T): lane holds d=dt*16+quad*4+r, q=mtQ*16+l15.
// LDS tiles use 32-u16-row panels (64B stride) to cut bank aliasing.
__global__ __launch_bounds__(256, 2) void flash_attn(const u16* __restrict__ Q,
                                                     const u16* __restrict__ K,
                                                     const u16* __restrict__ Vt,
                                                     u16* __restrict__ O) {
    __shared__ u16 lds_all[16384];           // 32 KB
    u16* Ks = lds_all;                       // [kc 2][key 64][dk 32]   (8 KB)
    u16* Vs = lds_all + 4096;                // [kc 2][d 64][key 32]    (8 KB)
    int tid = threadIdx.x, lane = tid & 63, wid = tid >> 6;
    u16* Ps = lds_all + 8192 + wid * 2048;   // per-wave [kc 2][q 32][key 32] (4 KB)
    int l15 = lane & 15, quad = lane >> 4;
    int h = blockIdx.y;
    int q0 = blockIdx.x * 128 + wid * 32;
    const u16* Qh = Q + (size_t)h * N_TOK * DHEAD;
    const u16* Kh = K + (size_t)h * N_TOK * DHEAD;
    const u16* Vh = Vt + (size_t)h * DHEAD * N_TOK;

    f32x4 zero4 = {0.f, 0.f, 0.f, 0.f};
    // Q fragments (B operand): B[n=q=l15][k=dhead]
    bf16x8 aq[2][2];
#pragma unroll
    for (int mtQ = 0; mtQ < 2; ++mtQ)
#pragma unroll
        for (int kc = 0; kc < 2; ++kc)
            aq[mtQ][kc] = *(const bf16x8*)&Qh[(size_t)(q0 + mtQ * 16 + l15) * DHEAD + kc * 32 + quad * 8];

    f32x4 o[2][4];
    float mrow[2], lrow[2];
#pragma unroll
    for (int mtQ = 0; mtQ < 2; ++mtQ) {
#pragma unroll
        for (int dt = 0; dt < 4; ++dt) o[mtQ][dt] = zero4;
        mrow[mtQ] = -1e30f; lrow[mtQ] = 0.f;
    }

    // staging: wave wid covers chunks c=2*wid, 2*wid+1; chunk c: panel kc=c&1, 16 rows r0=(c>>1)*16
    int c_a = wid * 2, c_b = wid * 2 + 1;
    int kcA = c_a & 1, r0A = (c_a >> 1) * 16;
    int kcB = c_b & 1, r0B = (c_b >> 1) * 16;
    int lrow4 = lane >> 2, lcol8 = (lane & 3) * 8;

    for (int kt = 0; kt < N_TOK; kt += 64) {
        // K: global row = key, col = dhead
        load_lds16(&Kh[(size_t)(kt + r0A + lrow4) * DHEAD + kcA * 32 + lcol8], &Ks[kcA * 2048 + r0A * 32]);
        load_lds16(&Kh[(size_t)(kt + r0B + lrow4) * DHEAD + kcB * 32 + lcol8], &Ks[kcB * 2048 + r0B * 32]);
        // V^T: global row = d, col = key
        load_lds16(&Vh[(size_t)(r0A + lrow4) * N_TOK + kt + kcA * 32 + lcol8], &Vs[kcA * 2048 + r0A * 32]);
        load_lds16(&Vh[(size_t)(r0B + lrow4) * N_TOK + kt + kcB * 32 + lcol8], &Vs[kcB * 2048 + r0B * 32]);
        __syncthreads();

        // fragment reads (then release LDS for next tile's staging)
        bf16x8 bk[4][2], av[4][2];
#pragma unroll
        for (int t = 0; t < 4; ++t)
#pragma unroll
            for (int kc = 0; kc < 2; ++kc) {
                bk[t][kc] = *(const bf16x8*)&Ks[kc * 2048 + (t * 16 + l15) * 32 + quad * 8];
                av[t][kc] = *(const bf16x8*)&Vs[kc * 2048 + (t * 16 + l15) * 32 + quad * 8];
            }
        __syncthreads();

#pragma unroll
        for (int mtQ = 0; mtQ < 2; ++mtQ) {
            // S^T: rows=key, cols=q
            f32x4 s[4];
#pragma unroll
            for (int ntK = 0; ntK < 4; ++ntK) {
                f32x4 t0 = __builtin_amdgcn_mfma_f32_16x16x32_bf16(bk[ntK][0], aq[mtQ][0], zero4, 0, 0, 0);
                s[ntK] = __builtin_amdgcn_mfma_f32_16x16x32_bf16(bk[ntK][1], aq[mtQ][1], t0, 0, 0, 0);
            }
            // per-lane softmax: all 16 values belong to q = mtQ*16+l15
            float mx = s[0][0];
#pragma unroll
            for (int ntK = 0; ntK < 4; ++ntK)
#pragma unroll
                for (int r = 0; r < 4; ++r) mx = fmaxf(mx, s[ntK][r]);
            mx = fmaxf(mx, __shfl_xor(mx, 16));
            mx = fmaxf(mx, __shfl_xor(mx, 32));
            float mold = mrow[mtQ];
            float mnew = fmaxf(mold, mx);
            mrow[mtQ] = mnew;
            float alpha = exp2f((mold - mnew) * SCALE_LOG2E);
            float rsum = 0.f;
#pragma unroll
            for (int ntK = 0; ntK < 4; ++ntK)
#pragma unroll
                for (int r = 0; r < 4; ++r) {
                    float p = exp2f((s[ntK][r] - mnew) * SCALE_LOG2E);
                    s[ntK][r] = p;
                    rsum += p;
                }
            rsum += __shfl_xor(rsum, 16);
            rsum += __shfl_xor(rsum, 32);
            lrow[mtQ] = lrow[mtQ] * alpha + rsum;
#pragma unroll
            for (int dt = 0; dt < 4; ++dt)
#pragma unroll
                for (int r = 0; r < 4; ++r) o[mtQ][dt][r] *= alpha;

            // store P^T panels: key = ntK*16+quad*4+r, q = mtQ*16+l15
#pragma unroll
            for (int ntK = 0; ntK < 4; ++ntK) {
                ushort4 pv;
                pv.x = f2bf(s[ntK][0]); pv.y = f2bf(s[ntK][1]);
                pv.z = f2bf(s[ntK][2]); pv.w = f2bf(s[ntK][3]);
                *(ushort4*)&Ps[(ntK >> 1) * 1024 + (mtQ * 16 + l15) * 32 + (ntK & 1) * 16 + quad * 4] = pv;
            }
            // reload as B operand: B[n=q=l15][k=key]
            bf16x8 bp0 = *(const bf16x8*)&Ps[(mtQ * 16 + l15) * 32 + quad * 8];
            bf16x8 bp1 = *(const bf16x8*)&Ps[1024 + (mtQ * 16 + l15) * 32 + quad * 8];
#pragma unroll
            for (int dt = 0; dt < 4; ++dt) {
                o[mtQ][dt] = __builtin_amdgcn_mfma_f32_16x16x32_bf16(av[dt][0], bp0, o[mtQ][dt], 0, 0, 0);
                o[mtQ][dt] = __builtin_amdgcn_mfma_f32_16x16x32_bf16(av[dt][1], bp1, o[mtQ][dt], 0, 0, 0);
            }
        }
    }

    // epilogue: transpose O^T -> O via per-wave LDS scratch, then coalesced write
    __syncthreads();
    u16* scratch = lds_all + wid * 2048;     // [q 32][d 64]
#pragma unroll
    for (int mtQ = 0; mtQ < 2; ++mtQ) {
        float rl = 1.f / lrow[mtQ];
#pragma unroll
        for (int dt = 0; dt < 4; ++dt) {
            ushort4 ov;
            ov.x = f2bf(o[mtQ][dt][0] * rl); ov.y = f2bf(o[mtQ][dt][1] * rl);
            ov.z = f2bf(o[mtQ][dt][2] * rl); ov.w = f2bf(o[mtQ][dt][3] * rl);
            *(ushort4*)&scratch[(mtQ * 16 + l15) * 64 + dt * 16 + quad * 4] = ov;
        }
    }
#pragma unroll
    for (int p = 0; p < 4; ++p) {
        int q_local = p * 8 + (lane >> 3);
        int dcol = (lane & 7) * 8;
        bf16x8 v = *(const bf16x8*)&scratch[q_local * 64 + dcol];
        *(bf16x8*)&O[(size_t)(q0 + q_local) * INNER + h * 64 + dcol] = v;
    }
}

extern "C" void kernel_launch(void* const* d_in, const int* in_sizes, int n_in,
                              void* d_out, int out_size, void* d_ws, size_t ws_size,
                              hipStream_t stream) {
    const float* x     = (const float*)d_in[0];
    const float* pe    = (const float*)d_in[1];
    const float* w_qkv = (const float*)d_in[2];
    const float* w_out = (const float*)d_in[3];
    const float* ln_g  = (const float*)d_in[4];
    const float* ln_b  = (const float*)d_in[5];
    float* out = (float*)d_out;

    char* ws = (char*)d_ws;
    u16* xn  = (u16*)ws;  ws += (size_t)N_TOK * DMODEL * 2;
    u16* wq  = (u16*)ws;  ws += (size_t)3 * INNER * DMODEL * 2;
    u16* wo  = (u16*)ws;  ws += (size_t)DMODEL * INNER * 2;
    u16* qkv = (u16*)ws;  ws += (size_t)N_TOK * DMODEL * 2;
    u16* Qr  = (u16*)ws;  ws += (size_t)NH * N_TOK * DHEAD * 2;
    u16* Kr  = (u16*)ws;  ws += (size_t)NH * N_TOK * DHEAD * 2;
    u16* Vt  = (u16*)ws;  ws += (size_t)NH * DHEAD * N_TOK * 2;
    u16* Ob  = (u16*)ws;  ws += (size_t)N_TOK * INNER * 2;

    ln_kernel<<<N_TOK, 256, 0, stream>>>(x, ln_g, ln_b, xn);
    {
        int n4 = 3 * INNER * DMODEL / 4;
        cvt_bf16<<<(n4 + 255) / 256, 256, 0, stream>>>(w_qkv, wq, n4);
    }
    {
        int n4 = DMODEL * INNER / 4;
        cvt_bf16<<<(n4 + 255) / 256, 256, 0, stream>>>(w_out, wo, n4);
    }
    gemm_bt<1><<<dim3(DMODEL / 128, N_TOK / 128), 256, 0, stream>>>(xn, wq, qkv, N_TOK, DMODEL, DMODEL);
    rope_qk<<<N_TOK, 256, 0, stream>>>(qkv, pe, Qr, Kr);
    v_transpose<<<dim3(N_TOK / 64, NH), 256, 0, stream>>>(qkv, Vt);
    flash_attn<<<dim3(N_TOK / 128, NH), 256, 0, stream>>>(Qr, Kr, Vt, Ob);
    gemm_bt<0><<<dim3(DMODEL / 128, N_TOK / 128), 256, 0, stream>>>(Ob, wo, out, N_TOK, DMODEL, INNER);
}

// Round 3
// 472.789 us; speedup vs baseline: 1.3109x; 1.0367x over previous
//
#include <hip/hip_runtime.h>
#include <hip/hip_bf16.h>

typedef unsigned short u16;
typedef __attribute__((ext_vector_type(8))) short bf16x8;
typedef __attribute__((ext_vector_type(4))) float f32x4;

#define N_TOK 4096
#define DMODEL 3072
#define NH 16
#define DHEAD 64
#define INNER 1024
#define SCALE_LOG2E 0.18033688011112042f  /* (1/8) * log2(e) */

__device__ __forceinline__ u16 f2bf(float f) {
    union { float f; unsigned u; } un; un.f = f;
    unsigned r = un.u + 0x7fffu + ((un.u >> 16) & 1u);
    return (u16)(r >> 16);
}
__device__ __forceinline__ float bf2f(u16 u) {
    union { unsigned u; float f; } x; x.u = ((unsigned)u) << 16; return x.f;
}
// pack two f32 -> two bf16 (round-half-up) in 3 VALU ops; a -> low 16
__device__ __forceinline__ unsigned pk2bf(float a, float b) {
    union { float f; unsigned u; } ua, ub; ua.f = a; ub.f = b;
    return __builtin_amdgcn_perm(ub.u + 0x8000u, ua.u + 0x8000u, 0x07060302u);
}
__device__ __forceinline__ void load_lds16(const u16* g, u16* l) {
    __builtin_amdgcn_global_load_lds(
        (const __attribute__((address_space(1))) unsigned int*)g,
        (__attribute__((address_space(3))) unsigned int*)l, 16, 0, 0);
}

// ---------------- LayerNorm: x f32 [4096,3072] -> xn bf16 ----------------
__global__ __launch_bounds__(256) void ln_kernel(const float* __restrict__ x,
                                                 const float* __restrict__ g,
                                                 const float* __restrict__ b,
                                                 u16* __restrict__ xn) {
    int row = blockIdx.x;
    int tid = threadIdx.x;
    const float4* xr = (const float4*)(x + (size_t)row * DMODEL);
    float4 v[3];
    float s = 0.f, ss = 0.f;
#pragma unroll
    for (int i = 0; i < 3; ++i) {
        v[i] = xr[i * 256 + tid];
        s  += v[i].x + v[i].y + v[i].z + v[i].w;
        ss += v[i].x * v[i].x + v[i].y * v[i].y + v[i].z * v[i].z + v[i].w * v[i].w;
    }
#pragma unroll
    for (int off = 32; off; off >>= 1) {
        s  += __shfl_xor(s, off);
        ss += __shfl_xor(ss, off);
    }
    __shared__ float red[8];
    int wid = tid >> 6, lane = tid & 63;
    if (lane == 0) { red[wid] = s; red[wid + 4] = ss; }
    __syncthreads();
    s  = red[0] + red[1] + red[2] + red[3];
    ss = red[4] + red[5] + red[6] + red[7];
    float mean = s * (1.f / DMODEL);
    float var  = ss * (1.f / DMODEL) - mean * mean;
    float rstd = rsqrtf(var + 1e-5f);
    ushort4* orow = (ushort4*)(xn + (size_t)row * DMODEL);
#pragma unroll
    for (int i = 0; i < 3; ++i) {
        float4 gg = ((const float4*)g)[i * 256 + tid];
        float4 bb = ((const float4*)b)[i * 256 + tid];
        ushort4 o;
        o.x = f2bf((v[i].x - mean) * rstd * gg.x + bb.x);
        o.y = f2bf((v[i].y - mean) * rstd * gg.y + bb.y);
        o.z = f2bf((v[i].z - mean) * rstd * gg.z + bb.z);
        o.w = f2bf((v[i].w - mean) * rstd * gg.w + bb.w);
        orow[i * 256 + tid] = o;
    }
}

// ---------------- f32 -> bf16 convert ----------------
__global__ __launch_bounds__(256) void cvt_bf16(const float* __restrict__ in,
                                                u16* __restrict__ out, int n4) {
    int i = blockIdx.x * 256 + threadIdx.x;
    if (i < n4) {
        float4 v = ((const float4*)in)[i];
        ushort4 o;
        o.x = f2bf(v.x); o.y = f2bf(v.y); o.z = f2bf(v.z); o.w = f2bf(v.w);
        ((ushort4*)out)[i] = o;
    }
}

// ---------------- GEMM C = A * B^T ; A[M,K], B[N,K] bf16, C f32 or bf16 ---
// 128x128 tile, BK=32; LDS rows 32 u16 with 16B-chunk XOR swizzle
// phys_chunk = chunk ^ ((row>>1)&3)  -> fragment reads 2-way (free)
template <int CBF16>
__global__ __launch_bounds__(256) void gemm_bt(const u16* __restrict__ A,
                                               const u16* __restrict__ B,
                                               void* __restrict__ C,
                                               int M, int Nn, int K) {
    __shared__ u16 As[128 * 32];
    __shared__ u16 Bs[128 * 32];
    int tid = threadIdx.x;
    int lane = tid & 63, wid = tid >> 6;
    int wm = wid >> 1, wn = wid & 1;
    int l15 = lane & 15, quad = lane >> 4;
    int m0 = blockIdx.y * 128, n0 = blockIdx.x * 128;

    f32x4 zero4 = {0.f, 0.f, 0.f, 0.f};
    f32x4 acc[4][4];
#pragma unroll
    for (int i = 0; i < 4; ++i)
#pragma unroll
        for (int j = 0; j < 4; ++j) acc[i][j] = zero4;

    const u16* Ab = A + (size_t)m0 * K;
    const u16* Bb = B + (size_t)n0 * K;
    int row0 = tid >> 2, c0 = (((tid & 3) ^ ((lane >> 3) & 3)) * 8);  // swizzled col
    int row1 = row0 + 64;
    int rsw = (l15 >> 1) & 3;

    for (int k0 = 0; k0 < K; k0 += 32) {
        load_lds16(Ab + (size_t)row0 * K + k0 + c0, &As[wid * 512]);
        load_lds16(Ab + (size_t)row1 * K + k0 + c0, &As[2048 + wid * 512]);
        load_lds16(Bb + (size_t)row0 * K + k0 + c0, &Bs[wid * 512]);
        load_lds16(Bb + (size_t)row1 * K + k0 + c0, &Bs[2048 + wid * 512]);
        __syncthreads();
        bf16x8 a[4], b[4];
#pragma unroll
        for (int t = 0; t < 4; ++t) {
            a[t] = *(const bf16x8*)&As[(wm * 64 + t * 16 + l15) * 32 + ((quad ^ rsw) * 8)];
            b[t] = *(const bf16x8*)&Bs[(wn * 64 + t * 16 + l15) * 32 + ((quad ^ rsw) * 8)];
        }
#pragma unroll
        for (int mt = 0; mt < 4; ++mt)
#pragma unroll
            for (int nt = 0; nt < 4; ++nt)
                acc[mt][nt] = __builtin_amdgcn_mfma_f32_16x16x32_bf16(a[mt], b[nt], acc[mt][nt], 0, 0, 0);
        __syncthreads();
    }
#pragma unroll
    for (int mt = 0; mt < 4; ++mt)
#pragma unroll
        for (int nt = 0; nt < 4; ++nt)
#pragma unroll
            for (int r = 0; r < 4; ++r) {
                int rr = m0 + wm * 64 + mt * 16 + quad * 4 + r;
                int cc = n0 + wn * 64 + nt * 16 + l15;
                if (CBF16)
                    ((u16*)C)[(size_t)rr * Nn + cc] = f2bf(acc[mt][nt][r]);
                else
                    ((float*)C)[(size_t)rr * Nn + cc] = acc[mt][nt][r];
            }
}

// ---------------- RoPE on q,k + reshape to [H,N,DH] ----------------
__global__ __launch_bounds__(256) void rope_qk(const u16* __restrict__ qkv,
                                               const float* __restrict__ pe,
                                               u16* __restrict__ Qr,
                                               u16* __restrict__ Kr) {
    int n = blockIdx.x;
    int tid = threadIdx.x;
    const u16* qrow = qkv + (size_t)n * DMODEL;
    const float4* pen = (const float4*)(pe + (size_t)n * 128);
#pragma unroll
    for (int it = 0; it < 2; ++it) {
        int p = it * 256 + tid;      // pair index 0..511
        int h = p >> 5, i = p & 31;
        float4 w = pen[i];
        size_t obase = ((size_t)h * N_TOK + n) * DHEAD + 2 * i;
        unsigned qq = *(const unsigned*)&qrow[h * 64 + 2 * i];
        float q0 = bf2f((u16)qq), q1 = bf2f((u16)(qq >> 16));
        *(unsigned*)&Qr[obase] = pk2bf(w.x * q0 + w.y * q1, w.z * q0 + w.w * q1);
        unsigned kk = *(const unsigned*)&qrow[INNER + h * 64 + 2 * i];
        float k0 = bf2f((u16)kk), k1 = bf2f((u16)(kk >> 16));
        *(unsigned*)&Kr[obase] = pk2bf(w.x * k0 + w.y * k1, w.z * k0 + w.w * k1);
    }
}

// ---------------- V transpose: Vt[h][d][n] = qkv[n][2048 + h*64 + d] ------
__global__ __launch_bounds__(256) void v_transpose(const u16* __restrict__ qkv,
                                                   u16* __restrict__ Vt) {
    __shared__ u16 t[64][65];
    int n0 = blockIdx.x * 64;
    int h = blockIdx.y;
    int tid = threadIdx.x;
#pragma unroll
    for (int it = 0; it < 4; ++it) {
        int nr = it * 16 + (tid >> 4);
        int dc = (tid & 15) * 4;
        ushort4 v = *(const ushort4*)&qkv[(size_t)(n0 + nr) * DMODEL + 2 * INNER + h * 64 + dc];
        t[dc + 0][nr] = v.x; t[dc + 1][nr] = v.y; t[dc + 2][nr] = v.z; t[dc + 3][nr] = v.w;
    }
    __syncthreads();
#pragma unroll
    for (int it = 0; it < 4; ++it) {
        int dr = it * 16 + (tid >> 4);
        int nc = (tid & 15) * 4;
        ushort4 v;
        v.x = t[dr][nc]; v.y = t[dr][nc + 1]; v.z = t[dr][nc + 2]; v.w = t[dr][nc + 3];
        *(ushort4*)&Vt[((size_t)h * 64 + dr) * N_TOK + n0 + nc] = v;
    }
}

// ---------------- Flash attention (transposed-S, swizzled LDS) ----------------
// grid (32 qtiles, 16 heads); 256 thr = 4 waves; wave owns 32 q-rows.
// S^T = mfma(A=K, B=Q): lane holds key=ntK*16+quad*4+r, q=mtQ*16+l15.
// O^T = mfma(A=V^T, B=P^T): lane holds d=dt*16+quad*4+r, q=mtQ*16+l15.
// LDS: 128B rows, 16B chunks, phys_chunk = chunk ^ (row&7) -> all frag r/w 2-way.
__global__ __launch_bounds__(256, 2) void flash_attn(const u16* __restrict__ Q,
                                                     const u16* __restrict__ K,
                                                     const u16* __restrict__ Vt,
                                                     u16* __restrict__ O) {
    __shared__ u16 lds_all[16384];           // 32 KB
    u16* Ks = lds_all;                       // [key 64][chunk 8][8]  (8 KB)
    u16* Vs = lds_all + 4096;                // [d 64][chunk 8][8]    (8 KB)
    int tid = threadIdx.x, lane = tid & 63, wid = tid >> 6;
    u16* Ps = lds_all + 8192 + wid * 2048;   // per-wave [q 32][chunk 8][8] (4 KB)
    int l15 = lane & 15, quad = lane >> 4;
    int sw = l15 & 7;
    int h = blockIdx.y;
    int q0 = blockIdx.x * 128 + wid * 32;
    const u16* Qh = Q + (size_t)h * N_TOK * DHEAD;
    const u16* Kh = K + (size_t)h * N_TOK * DHEAD;
    const u16* Vh = Vt + (size_t)h * DHEAD * N_TOK;

    f32x4 zero4 = {0.f, 0.f, 0.f, 0.f};
    // Q fragments (B operand): B[n=q=l15][k=dhead]
    bf16x8 aq[2][2];
#pragma unroll
    for (int mtQ = 0; mtQ < 2; ++mtQ)
#pragma unroll
        for (int kc = 0; kc < 2; ++kc)
            aq[mtQ][kc] = *(const bf16x8*)&Qh[(size_t)(q0 + mtQ * 16 + l15) * DHEAD + kc * 32 + quad * 8];

    f32x4 o[2][4];
    float mrow[2], lrow[2];
#pragma unroll
    for (int mtQ = 0; mtQ < 2; ++mtQ) {
#pragma unroll
        for (int dt = 0; dt < 4; ++dt) o[mtQ][dt] = zero4;
        mrow[mtQ] = -1e30f; lrow[mtQ] = 0.f;
    }

    // staging: wave stages rows [wid*16, wid*16+16) of both K and V^T tiles.
    // LDS dest is wave-linear; XOR swizzle applied to the GLOBAL source column.
    int rbase = wid * 16;
    int rowoff = lane >> 3;                      // 0..7
    int csw = ((lane & 7) ^ rowoff) * 8;         // swizzled source column (u16)

    for (int kt = 0; kt < N_TOK; kt += 64) {
        load_lds16(&Kh[(size_t)(kt + rbase + rowoff) * DHEAD + csw], &Ks[rbase * 64]);
        load_lds16(&Kh[(size_t)(kt + rbase + 8 + rowoff) * DHEAD + csw], &Ks[(rbase + 8) * 64]);
        load_lds16(&Vh[(size_t)(rbase + rowoff) * N_TOK + kt + csw], &Vs[rbase * 64]);
        load_lds16(&Vh[(size_t)(rbase + 8 + rowoff) * N_TOK + kt + csw], &Vs[(rbase + 8) * 64]);
        __syncthreads();

        // fragment reads (then release LDS for next tile's staging)
        bf16x8 bk[4][2], av[4][2];
#pragma unroll
        for (int t = 0; t < 4; ++t)
#pragma unroll
            for (int kc = 0; kc < 2; ++kc) {
                int off = (t * 16 + l15) * 64 + (((kc * 4 + quad) ^ sw) * 8);
                bk[t][kc] = *(const bf16x8*)&Ks[off];
                av[t][kc] = *(const bf16x8*)&Vs[off];
            }
        __syncthreads();

#pragma unroll
        for (int mtQ = 0; mtQ < 2; ++mtQ) {
            // S^T: rows=key, cols=q
            f32x4 s[4];
#pragma unroll
            for (int ntK = 0; ntK < 4; ++ntK) {
                f32x4 t0 = __builtin_amdgcn_mfma_f32_16x16x32_bf16(bk[ntK][0], aq[mtQ][0], zero4, 0, 0, 0);
                s[ntK] = __builtin_amdgcn_mfma_f32_16x16x32_bf16(bk[ntK][1], aq[mtQ][1], t0, 0, 0, 0);
            }
            // per-lane softmax: all 16 values belong to q = mtQ*16+l15
            float mx = s[0][0];
#pragma unroll
            for (int ntK = 0; ntK < 4; ++ntK)
#pragma unroll
                for (int r = 0; r < 4; ++r) mx = fmaxf(mx, s[ntK][r]);
            mx = fmaxf(mx, __shfl_xor(mx, 16));
            mx = fmaxf(mx, __shfl_xor(mx, 32));
            float mold = mrow[mtQ];
            float mnew = fmaxf(mold, mx);
            mrow[mtQ] = mnew;
            float alpha = exp2f((mold - mnew) * SCALE_LOG2E);
            float rsum = 0.f;
#pragma unroll
            for (int ntK = 0; ntK < 4; ++ntK)
#pragma unroll
                for (int r = 0; r < 4; ++r) {
                    float p = exp2f((s[ntK][r] - mnew) * SCALE_LOG2E);
                    s[ntK][r] = p;
                    rsum += p;
                }
            rsum += __shfl_xor(rsum, 16);
            rsum += __shfl_xor(rsum, 32);
            lrow[mtQ] = lrow[mtQ] * alpha + rsum;
#pragma unroll
            for (int dt = 0; dt < 4; ++dt)
#pragma unroll
                for (int r = 0; r < 4; ++r) o[mtQ][dt][r] *= alpha;

            // store P^T: key = ntK*16+quad*4+r, q = mtQ*16+l15 (swizzled chunks)
#pragma unroll
            for (int ntK = 0; ntK < 4; ++ntK) {
                uint2 pv;
                pv.x = pk2bf(s[ntK][0], s[ntK][1]);
                pv.y = pk2bf(s[ntK][2], s[ntK][3]);
                int pc = (ntK * 2 + (quad >> 1)) ^ sw;
                *(uint2*)&Ps[(mtQ * 16 + l15) * 64 + pc * 8 + (quad & 1) * 4] = pv;
            }
            // reload as B operand: B[n=q=l15][k=key]
            bf16x8 bp0 = *(const bf16x8*)&Ps[(mtQ * 16 + l15) * 64 + ((quad ^ sw) * 8)];
            bf16x8 bp1 = *(const bf16x8*)&Ps[(mtQ * 16 + l15) * 64 + (((4 + quad) ^ sw) * 8)];
#pragma unroll
            for (int dt = 0; dt < 4; ++dt) {
                o[mtQ][dt] = __builtin_amdgcn_mfma_f32_16x16x32_bf16(av[dt][0], bp0, o[mtQ][dt], 0, 0, 0);
                o[mtQ][dt] = __builtin_amdgcn_mfma_f32_16x16x32_bf16(av[dt][1], bp1, o[mtQ][dt], 0, 0, 0);
            }
        }
    }

    // epilogue: transpose O^T -> O via per-wave LDS scratch, then coalesced write
    __syncthreads();
    u16* scratch = lds_all + wid * 2048;     // [q 32][d 64]
#pragma unroll
    for (int mtQ = 0; mtQ < 2; ++mtQ) {
        float rl = 1.f / lrow[mtQ];
#pragma unroll
        for (int dt = 0; dt < 4; ++dt) {
            uint2 ov;
            ov.x = pk2bf(o[mtQ][dt][0] * rl, o[mtQ][dt][1] * rl);
            ov.y = pk2bf(o[mtQ][dt][2] * rl, o[mtQ][dt][3] * rl);
            *(uint2*)&scratch[(mtQ * 16 + l15) * 64 + dt * 16 + quad * 4] = ov;
        }
    }
#pragma unroll
    for (int p = 0; p < 4; ++p) {
        int q_local = p * 8 + (lane >> 3);
        int dcol = (lane & 7) * 8;
        bf16x8 v = *(const bf16x8*)&scratch[q_local * 64 + dcol];
        *(bf16x8*)&O[(size_t)(q0 + q_local) * INNER + h * 64 + dcol] = v;
    }
}

extern "C" void kernel_launch(void* const* d_in, const int* in_sizes, int n_in,
                              void* d_out, int out_size, void* d_ws, size_t ws_size,
                              hipStream_t stream) {
    const float* x     = (const float*)d_in[0];
    const float* pe    = (const float*)d_in[1];
    const float* w_qkv = (const float*)d_in[2];
    const float* w_out = (const float*)d_in[3];
    const float* ln_g  = (const float*)d_in[4];
    const float* ln_b  = (const float*)d_in[5];
    float* out = (float*)d_out;

    char* ws = (char*)d_ws;
    u16* xn  = (u16*)ws;  ws += (size_t)N_TOK * DMODEL * 2;
    u16* wq  = (u16*)ws;  ws += (size_t)3 * INNER * DMODEL * 2;
    u16* wo  = (u16*)ws;  ws += (size_t)DMODEL * INNER * 2;
    u16* qkv = (u16*)ws;  ws += (size_t)N_TOK * DMODEL * 2;
    u16* Qr  = (u16*)ws;  ws += (size_t)NH * N_TOK * DHEAD * 2;
    u16* Kr  = (u16*)ws;  ws += (size_t)NH * N_TOK * DHEAD * 2;
    u16* Vt  = (u16*)ws;  ws += (size_t)NH * DHEAD * N_TOK * 2;
    u16* Ob  = (u16*)ws;  ws += (size_t)N_TOK * INNER * 2;

    ln_kernel<<<N_TOK, 256, 0, stream>>>(x, ln_g, ln_b, xn);
    {
        int n4 = 3 * INNER * DMODEL / 4;
        cvt_bf16<<<(n4 + 255) / 256, 256, 0, stream>>>(w_qkv, wq, n4);
    }
    {
        int n4 = DMODEL * INNER / 4;
        cvt_bf16<<<(n4 + 255) / 256, 256, 0, stream>>>(w_out, wo, n4);
    }
    gemm_bt<1><<<dim3(DMODEL / 128, N_TOK / 128), 256, 0, stream>>>(xn, wq, qkv, N_TOK, DMODEL, DMODEL);
    rope_qk<<<N_TOK, 256, 0, stream>>>(qkv, pe, Qr, Kr);
    v_transpose<<<dim3(N_TOK / 64, NH), 256, 0, stream>>>(qkv, Vt);
    flash_attn<<<dim3(N_TOK / 128, NH), 256, 0, stream>>>(Qr, Kr, Vt, Ob);
    gemm_bt<0><<<dim3(DMODEL / 128, N_TOK / 128), 256, 0, stream>>>(Ob, wo, out, N_TOK, DMODEL, INNER);
}

// Round 6
// 400.478 us; speedup vs baseline: 1.5476x; 1.1806x over previous
//
#include <hip/hip_runtime.h>
#include <hip/hip_bf16.h>

typedef unsigned short u16;
typedef __attribute__((ext_vector_type(8))) short bf16x8;
typedef __attribute__((ext_vector_type(4))) float f32x4;

#define N_TOK 4096
#define DMODEL 3072
#define NH 16
#define DHEAD 64
#define INNER 1024
#define SCALE_LOG2E 0.18033688011112042f  /* (1/8) * log2(e) */

__device__ __forceinline__ u16 f2bf(float f) {
    union { float f; unsigned u; } un; un.f = f;
    unsigned r = un.u + 0x7fffu + ((un.u >> 16) & 1u);
    return (u16)(r >> 16);
}
__device__ __forceinline__ float bf2f(u16 u) {
    union { unsigned u; float f; } x; x.u = ((unsigned)u) << 16; return x.f;
}
// pack two f32 -> two bf16 (round-half-up) in 3 VALU ops; a -> low 16
__device__ __forceinline__ unsigned pk2bf(float a, float b) {
    union { float f; unsigned u; } ua, ub; ua.f = a; ub.f = b;
    return __builtin_amdgcn_perm(ub.u + 0x8000u, ua.u + 0x8000u, 0x07060302u);
}
__device__ __forceinline__ void load_lds16(const u16* g, u16* l) {
    __builtin_amdgcn_global_load_lds(
        (const __attribute__((address_space(1))) unsigned int*)g,
        (__attribute__((address_space(3))) unsigned int*)l, 16, 0, 0);
}

// ---------------- LayerNorm: x f32 [4096,3072] -> xn bf16 ----------------
__global__ __launch_bounds__(256) void ln_kernel(const float* __restrict__ x,
                                                 const float* __restrict__ g,
                                                 const float* __restrict__ b,
                                                 u16* __restrict__ xn) {
    int row = blockIdx.x;
    int tid = threadIdx.x;
    const float4* xr = (const float4*)(x + (size_t)row * DMODEL);
    float4 v[3];
    float s = 0.f, ss = 0.f;
#pragma unroll
    for (int i = 0; i < 3; ++i) {
        v[i] = xr[i * 256 + tid];
        s  += v[i].x + v[i].y + v[i].z + v[i].w;
        ss += v[i].x * v[i].x + v[i].y * v[i].y + v[i].z * v[i].z + v[i].w * v[i].w;
    }
#pragma unroll
    for (int off = 32; off; off >>= 1) {
        s  += __shfl_xor(s, off);
        ss += __shfl_xor(ss, off);
    }
    __shared__ float red[8];
    int wid = tid >> 6, lane = tid & 63;
    if (lane == 0) { red[wid] = s; red[wid + 4] = ss; }
    __syncthreads();
    s  = red[0] + red[1] + red[2] + red[3];
    ss = red[4] + red[5] + red[6] + red[7];
    float mean = s * (1.f / DMODEL);
    float var  = ss * (1.f / DMODEL) - mean * mean;
    float rstd = rsqrtf(var + 1e-5f);
    ushort4* orow = (ushort4*)(xn + (size_t)row * DMODEL);
#pragma unroll
    for (int i = 0; i < 3; ++i) {
        float4 gg = ((const float4*)g)[i * 256 + tid];
        float4 bb = ((const float4*)b)[i * 256 + tid];
        ushort4 o;
        o.x = f2bf((v[i].x - mean) * rstd * gg.x + bb.x);
        o.y = f2bf((v[i].y - mean) * rstd * gg.y + bb.y);
        o.z = f2bf((v[i].z - mean) * rstd * gg.z + bb.z);
        o.w = f2bf((v[i].w - mean) * rstd * gg.w + bb.w);
        orow[i * 256 + tid] = o;
    }
}

// ---------------- f32 -> bf16 convert ----------------
__global__ __launch_bounds__(256) void cvt_bf16(const float* __restrict__ in,
                                                u16* __restrict__ out, int n4) {
    int i = blockIdx.x * 256 + threadIdx.x;
    if (i < n4) {
        float4 v = ((const float4*)in)[i];
        ushort4 o;
        o.x = f2bf(v.x); o.y = f2bf(v.y); o.z = f2bf(v.z); o.w = f2bf(v.w);
        ((ushort4*)out)[i] = o;
    }
}

// ---------------- GEMM C = A * B^T ; A[M,K], B[N,K] bf16, C f32 or bf16 ---
template <int CBF16>
__global__ __launch_bounds__(256) void gemm_bt(const u16* __restrict__ A,
                                               const u16* __restrict__ B,
                                               void* __restrict__ C,
                                               int M, int Nn, int K) {
    __shared__ u16 As[128 * 32];
    __shared__ u16 Bs[128 * 32];
    int tid = threadIdx.x;
    int lane = tid & 63, wid = tid >> 6;
    int wm = wid >> 1, wn = wid & 1;
    int l15 = lane & 15, quad = lane >> 4;
    int m0 = blockIdx.y * 128, n0 = blockIdx.x * 128;

    f32x4 zero4 = {0.f, 0.f, 0.f, 0.f};
    f32x4 acc[4][4];
#pragma unroll
    for (int i = 0; i < 4; ++i)
#pragma unroll
        for (int j = 0; j < 4; ++j) acc[i][j] = zero4;

    const u16* Ab = A + (size_t)m0 * K;
    const u16* Bb = B + (size_t)n0 * K;
    int row0 = tid >> 2, c0 = (((tid & 3) ^ ((lane >> 3) & 3)) * 8);  // swizzled col
    int row1 = row0 + 64;
    int rsw = (l15 >> 1) & 3;

    for (int k0 = 0; k0 < K; k0 += 32) {
        load_lds16(Ab + (size_t)row0 * K + k0 + c0, &As[wid * 512]);
        load_lds16(Ab + (size_t)row1 * K + k0 + c0, &As[2048 + wid * 512]);
        load_lds16(Bb + (size_t)row0 * K + k0 + c0, &Bs[wid * 512]);
        load_lds16(Bb + (size_t)row1 * K + k0 + c0, &Bs[2048 + wid * 512]);
        __syncthreads();
        bf16x8 a[4], b[4];
#pragma unroll
        for (int t = 0; t < 4; ++t) {
            a[t] = *(const bf16x8*)&As[(wm * 64 + t * 16 + l15) * 32 + ((quad ^ rsw) * 8)];
            b[t] = *(const bf16x8*)&Bs[(wn * 64 + t * 16 + l15) * 32 + ((quad ^ rsw) * 8)];
        }
#pragma unroll
        for (int mt = 0; mt < 4; ++mt)
#pragma unroll
            for (int nt = 0; nt < 4; ++nt)
                acc[mt][nt] = __builtin_amdgcn_mfma_f32_16x16x32_bf16(a[mt], b[nt], acc[mt][nt], 0, 0, 0);
        __syncthreads();
    }
#pragma unroll
    for (int mt = 0; mt < 4; ++mt)
#pragma unroll
        for (int nt = 0; nt < 4; ++nt)
#pragma unroll
            for (int r = 0; r < 4; ++r) {
                int rr = m0 + wm * 64 + mt * 16 + quad * 4 + r;
                int cc = n0 + wn * 64 + nt * 16 + l15;
                if (CBF16)
                    ((u16*)C)[(size_t)rr * Nn + cc] = f2bf(acc[mt][nt][r]);
                else
                    ((float*)C)[(size_t)rr * Nn + cc] = acc[mt][nt][r];
            }
}

// ---------------- RoPE on q,k + reshape to [H,N,DH] ----------------
// Q is pre-scaled by (1/8)*log2(e) so flash's exp2 needs no multiply.
__global__ __launch_bounds__(256) void rope_qk(const u16* __restrict__ qkv,
                                               const float* __restrict__ pe,
                                               u16* __restrict__ Qr,
                                               u16* __restrict__ Kr) {
    int n = blockIdx.x;
    int tid = threadIdx.x;
    const u16* qrow = qkv + (size_t)n * DMODEL;
    const float4* pen = (const float4*)(pe + (size_t)n * 128);
#pragma unroll
    for (int it = 0; it < 2; ++it) {
        int p = it * 256 + tid;      // pair index 0..511
        int h = p >> 5, i = p & 31;
        float4 w = pen[i];
        size_t obase = ((size_t)h * N_TOK + n) * DHEAD + 2 * i;
        unsigned qq = *(const unsigned*)&qrow[h * 64 + 2 * i];
        float q0 = bf2f((u16)qq), q1 = bf2f((u16)(qq >> 16));
        *(unsigned*)&Qr[obase] = pk2bf((w.x * q0 + w.y * q1) * SCALE_LOG2E,
                                       (w.z * q0 + w.w * q1) * SCALE_LOG2E);
        unsigned kk = *(const unsigned*)&qrow[INNER + h * 64 + 2 * i];
        float k0 = bf2f((u16)kk), k1 = bf2f((u16)(kk >> 16));
        *(unsigned*)&Kr[obase] = pk2bf(w.x * k0 + w.y * k1, w.z * k0 + w.w * k1);
    }
}

// ---------------- V transpose: Vt[h][d][n] = qkv[n][2048 + h*64 + d] ------
__global__ __launch_bounds__(256) void v_transpose(const u16* __restrict__ qkv,
                                                   u16* __restrict__ Vt) {
    __shared__ u16 t[64][65];
    int n0 = blockIdx.x * 64;
    int h = blockIdx.y;
    int tid = threadIdx.x;
#pragma unroll
    for (int it = 0; it < 4; ++it) {
        int nr = it * 16 + (tid >> 4);
        int dc = (tid & 15) * 4;
        ushort4 v = *(const ushort4*)&qkv[(size_t)(n0 + nr) * DMODEL + 2 * INNER + h * 64 + dc];
        t[dc + 0][nr] = v.x; t[dc + 1][nr] = v.y; t[dc + 2][nr] = v.z; t[dc + 3][nr] = v.w;
    }
    __syncthreads();
#pragma unroll
    for (int it = 0; it < 4; ++it) {
        int dr = it * 16 + (tid >> 4);
        int nc = (tid & 15) * 4;
        ushort4 v;
        v.x = t[dr][nc]; v.y = t[dr][nc + 1]; v.z = t[dr][nc + 2]; v.w = t[dr][nc + 3];
        *(ushort4*)&Vt[((size_t)h * 64 + dr) * N_TOK + n0 + nc] = v;
    }
}

// ---------------- Flash attention (fixed-bias softmax, no online max) -----
// grid (32 qtiles, 16 heads); 256 thr = 4 waves; wave owns 32 q-rows.
// Q pre-scaled so S^T (bf16 MFMA) is directly the exp2 argument.
// p = exp2(s) raw, carried in BF16 (range 2^127 — raw p can reach ~2^30,
// which overflows f16; f16 attempt failed R5). l via ones-row MFMA.
__global__ __launch_bounds__(256, 2) void flash_attn(const u16* __restrict__ Q,
                                                     const u16* __restrict__ K,
                                                     const u16* __restrict__ Vt,
                                                     u16* __restrict__ O) {
    __shared__ u16 lds_all[16384];           // 32 KB
    u16* Ks = lds_all;                       // [key 64][chunk 8][8]  (8 KB) bf16
    u16* Vs = lds_all + 4096;                // [d 64][chunk 8][8]    (8 KB) bf16
    int tid = threadIdx.x, lane = tid & 63, wid = tid >> 6;
    u16* Ps = lds_all + 8192 + wid * 2048;   // per-wave [q 32][chunk 8][8] (4 KB) bf16
    int l15 = lane & 15, quad = lane >> 4;
    int sw = l15 & 7;
    int h = blockIdx.y;
    int q0 = blockIdx.x * 128 + wid * 32;
    const u16* Qh = Q + (size_t)h * N_TOK * DHEAD;
    const u16* Kh = K + (size_t)h * N_TOK * DHEAD;
    const u16* Vh = Vt + (size_t)h * DHEAD * N_TOK;

    f32x4 zero4 = {0.f, 0.f, 0.f, 0.f};
    bf16x8 ones;
#pragma unroll
    for (int i = 0; i < 8; ++i) ones[i] = (short)0x3F80;  // bf16 1.0

    // Q fragments (B operand): B[n=q=l15][k=dhead]
    bf16x8 aq[2][2];
#pragma unroll
    for (int mtQ = 0; mtQ < 2; ++mtQ)
#pragma unroll
        for (int kc = 0; kc < 2; ++kc)
            aq[mtQ][kc] = *(const bf16x8*)&Qh[(size_t)(q0 + mtQ * 16 + l15) * DHEAD + kc * 32 + quad * 8];

    f32x4 o[2][4], lacc[2];
#pragma unroll
    for (int mtQ = 0; mtQ < 2; ++mtQ) {
#pragma unroll
        for (int dt = 0; dt < 4; ++dt) o[mtQ][dt] = zero4;
        lacc[mtQ] = zero4;
    }

    // staging: wave stages rows [wid*16, wid*16+16); XOR swizzle on global col
    int rbase = wid * 16;
    int rowoff = lane >> 3;                      // 0..7
    int csw = ((lane & 7) ^ rowoff) * 8;         // swizzled source column (u16)

    for (int kt = 0; kt < N_TOK; kt += 64) {
        load_lds16(&Kh[(size_t)(kt + rbase + rowoff) * DHEAD + csw], &Ks[rbase * 64]);
        load_lds16(&Kh[(size_t)(kt + rbase + 8 + rowoff) * DHEAD + csw], &Ks[(rbase + 8) * 64]);
        load_lds16(&Vh[(size_t)(rbase + rowoff) * N_TOK + kt + csw], &Vs[rbase * 64]);
        load_lds16(&Vh[(size_t)(rbase + 8 + rowoff) * N_TOK + kt + csw], &Vs[(rbase + 8) * 64]);
        __syncthreads();

        bf16x8 bk[4][2], av[4][2];
#pragma unroll
        for (int t = 0; t < 4; ++t)
#pragma unroll
            for (int kc = 0; kc < 2; ++kc) {
                int off = (t * 16 + l15) * 64 + (((kc * 4 + quad) ^ sw) * 8);
                bk[t][kc] = *(const bf16x8*)&Ks[off];
                av[t][kc] = *(const bf16x8*)&Vs[off];
            }
        __syncthreads();

#pragma unroll
        for (int mtQ = 0; mtQ < 2; ++mtQ) {
            // S^T: rows=key, cols=q (already in log2-exp domain via Q pre-scale)
            f32x4 s[4];
#pragma unroll
            for (int ntK = 0; ntK < 4; ++ntK) {
                f32x4 t0 = __builtin_amdgcn_mfma_f32_16x16x32_bf16(bk[ntK][0], aq[mtQ][0], zero4, 0, 0, 0);
                s[ntK] = __builtin_amdgcn_mfma_f32_16x16x32_bf16(bk[ntK][1], aq[mtQ][1], t0, 0, 0, 0);
            }
            // p = exp2(s); pack to bf16 and store P^T (swizzled chunks)
#pragma unroll
            for (int ntK = 0; ntK < 4; ++ntK) {
                uint2 pv;
                pv.x = pk2bf(__builtin_amdgcn_exp2f(s[ntK][0]), __builtin_amdgcn_exp2f(s[ntK][1]));
                pv.y = pk2bf(__builtin_amdgcn_exp2f(s[ntK][2]), __builtin_amdgcn_exp2f(s[ntK][3]));
                int pc = (ntK * 2 + (quad >> 1)) ^ sw;
                *(uint2*)&Ps[(mtQ * 16 + l15) * 64 + pc * 8 + (quad & 1) * 4] = pv;
            }
            // reload as B operand: B[n=q=l15][k=key]
            bf16x8 bp0 = *(const bf16x8*)&Ps[(mtQ * 16 + l15) * 64 + ((quad ^ sw) * 8)];
            bf16x8 bp1 = *(const bf16x8*)&Ps[(mtQ * 16 + l15) * 64 + (((4 + quad) ^ sw) * 8)];
            // l += sum_k P (ones-row MFMA; every lane gets l(q) in all 4 elems)
            lacc[mtQ] = __builtin_amdgcn_mfma_f32_16x16x32_bf16(ones, bp0, lacc[mtQ], 0, 0, 0);
            lacc[mtQ] = __builtin_amdgcn_mfma_f32_16x16x32_bf16(ones, bp1, lacc[mtQ], 0, 0, 0);
#pragma unroll
            for (int dt = 0; dt < 4; ++dt) {
                o[mtQ][dt] = __builtin_amdgcn_mfma_f32_16x16x32_bf16(av[dt][0], bp0, o[mtQ][dt], 0, 0, 0);
                o[mtQ][dt] = __builtin_amdgcn_mfma_f32_16x16x32_bf16(av[dt][1], bp1, o[mtQ][dt], 0, 0, 0);
            }
        }
    }

    // epilogue: transpose O^T -> O via per-wave LDS scratch, then coalesced write
    __syncthreads();
    u16* scratch = lds_all + wid * 2048;     // [q 32][d 64]
#pragma unroll
    for (int mtQ = 0; mtQ < 2; ++mtQ) {
        float rl = 1.f / lacc[mtQ][0];
#pragma unroll
        for (int dt = 0; dt < 4; ++dt) {
            uint2 ov;
            ov.x = pk2bf(o[mtQ][dt][0] * rl, o[mtQ][dt][1] * rl);
            ov.y = pk2bf(o[mtQ][dt][2] * rl, o[mtQ][dt][3] * rl);
            *(uint2*)&scratch[(mtQ * 16 + l15) * 64 + dt * 16 + quad * 4] = ov;
        }
    }
#pragma unroll
    for (int p = 0; p < 4; ++p) {
        int q_local = p * 8 + (lane >> 3);
        int dcol = (lane & 7) * 8;
        bf16x8 v = *(const bf16x8*)&scratch[q_local * 64 + dcol];
        *(bf16x8*)&O[(size_t)(q0 + q_local) * INNER + h * 64 + dcol] = v;
    }
}

extern "C" void kernel_launch(void* const* d_in, const int* in_sizes, int n_in,
                              void* d_out, int out_size, void* d_ws, size_t ws_size,
                              hipStream_t stream) {
    const float* x     = (const float*)d_in[0];
    const float* pe    = (const float*)d_in[1];
    const float* w_qkv = (const float*)d_in[2];
    const float* w_out = (const float*)d_in[3];
    const float* ln_g  = (const float*)d_in[4];
    const float* ln_b  = (const float*)d_in[5];
    float* out = (float*)d_out;

    char* ws = (char*)d_ws;
    u16* xn  = (u16*)ws;  ws += (size_t)N_TOK * DMODEL * 2;
    u16* wq  = (u16*)ws;  ws += (size_t)3 * INNER * DMODEL * 2;
    u16* wo  = (u16*)ws;  ws += (size_t)DMODEL * INNER * 2;
    u16* qkv = (u16*)ws;  ws += (size_t)N_TOK * DMODEL * 2;
    u16* Qr  = (u16*)ws;  ws += (size_t)NH * N_TOK * DHEAD * 2;
    u16* Kr  = (u16*)ws;  ws += (size_t)NH * N_TOK * DHEAD * 2;
    u16* Vt  = (u16*)ws;  ws += (size_t)NH * DHEAD * N_TOK * 2;
    u16* Ob  = (u16*)ws;  ws += (size_t)N_TOK * INNER * 2;

    ln_kernel<<<N_TOK, 256, 0, stream>>>(x, ln_g, ln_b, xn);
    {
        int n4 = 3 * INNER * DMODEL / 4;
        cvt_bf16<<<(n4 + 255) / 256, 256, 0, stream>>>(w_qkv, wq, n4);
    }
    {
        int n4 = DMODEL * INNER / 4;
        cvt_bf16<<<(n4 + 255) / 256, 256, 0, stream>>>(w_out, wo, n4);
    }
    gemm_bt<1><<<dim3(DMODEL / 128, N_TOK / 128), 256, 0, stream>>>(xn, wq, qkv, N_TOK, DMODEL, DMODEL);
    rope_qk<<<N_TOK, 256, 0, stream>>>(qkv, pe, Qr, Kr);
    v_transpose<<<dim3(N_TOK / 64, NH), 256, 0, stream>>>(qkv, Vt);
    flash_attn<<<dim3(N_TOK / 128, NH), 256, 0, stream>>>(Qr, Kr, Vt, Ob);
    gemm_bt<0><<<dim3(DMODEL / 128, N_TOK / 128), 256, 0, stream>>>(Ob, wo, out, N_TOK, DMODEL, INNER);
}